// Round 6
// baseline (378.477 us; speedup 1.0000x reference)
//
#include <hip/hip_runtime.h>

#define WW 1024
#define HH 1024
#define NIMG 2
#define NCH 8
#define HWSZ (HH * WW)
#define CHW (NCH * HWSZ)
#define NBLK_MASK 2048
#define NBLK_MAIN 4096
// ws u32 layout: [0..2047] block mins, [2048..4095] block maxs,
// [4096] sum, [4097] cnt, [4098] ticket,
// dv16 (packed unorm16 mask diff, 1M u32) at 4352,
// qt (quantized+haloed target) at WS_QT16.
#define WS_SUM 4096
#define WS_CNT 4097
#define WS_TKT 4098
#define WS_DV16 4352
#define WS_QT16 (4352 + HWSZ)   // u32 index; qt = 2img*4cp*1024rows*2halves*136 uint4

typedef unsigned int uint;

__device__ __forceinline__ uint pknorm(float a, float b) {
    uint d;
    asm("v_cvt_pknorm_u16_f32 %0, %1, %2" : "=v"(d) : "v"(a), "v"(b));
    return d;
}
__device__ __forceinline__ uint sadu16(uint a, uint b, uint c) {
    uint d;
    asm("v_sad_u16 %0, %1, %2, %3" : "=v"(d) : "v"(a), "v"(b), "v"(c));
    return d;
}
__device__ __forceinline__ int reflect_idx(int t) {
    if (t < 0) t = -t;
    if (t > HH - 1) t = 2 * (HH - 1) - t;
    return t;
}
// padded-granule -> slot (E granules first, then O)
__device__ __forceinline__ int gp2slot(int gp) {
    return (gp & 1) ? (68 + (gp >> 1)) : (gp >> 1);
}

#define GLD16(g, l)                                                         \
    __builtin_amdgcn_global_load_lds(                                       \
        (const __attribute__((address_space(1))) uint*)(g),                 \
        (__attribute__((address_space(3))) uint*)(l), 16, 0, 0)

// Pass 0: quantize tgt to unorm16 chpairs; emit per (n,cp,row,half) a 136-uint4
// record, slot-indexed (E/O deinterleaved) with reflected col-halos baked in.
__global__ __launch_bounds__(256) void k_quant(const float* __restrict__ tgt,
                                               uint4* __restrict__ qt4) {
    int b = blockIdx.x;            // (n*4+cp)*1024 + row
    int t = threadIdx.x;           // image granule 0..255
    int row = b & 1023;
    int pcp = b >> 10;             // n*4+cp
    int n = pcp >> 2, cp = pcp & 3;
    const float* c0 = tgt + (size_t)(n * NCH + 2 * cp) * HWSZ + (size_t)row * WW;

    float4 a = *(const float4*)(c0 + 4 * t);
    float4 c = *(const float4*)(c0 + 4 * t + HWSZ);
    uint4 u;
    u.x = pknorm(a.x, c.x); u.y = pknorm(a.y, c.y);
    u.z = pknorm(a.z, c.z); u.w = pknorm(a.w, c.w);

    uint4* rbase = qt4 + (((size_t)b) * 2) * 136;   // half0 record; half1 = +136
    int g = t;
    if (g <= 131) rbase[gp2slot(g + 4)] = u;                 // half0 interior
    if (g >= 124) rbase[136 + gp2slot(g - 124)] = u;         // half1 interior

    // halos with reflection: 8 granules per (row,cp): half0 gp0..3, half1 gp132..135
    if (t < 8) {
        int which = t >> 2;                 // 0 = half0 low, 1 = half1 high
        int gp = (t & 3) + (which ? 132 : 0);
        uint4 hv;
        uint* hw = (uint*)&hv;
#pragma unroll
        for (int k = 0; k < 4; ++k) {
            int pc = 4 * gp + k;
            int j = which ? (1550 - pc) : (16 - pc);  // reflected image col
            hw[k] = pknorm(c0[j], c0[j + HWSZ]);
        }
        rbase[which * 136 + gp2slot(gp)] = hv;
    }
}

// Pass 1: mask diff d = |mean_c(msO) - pan| -> packed unorm16; per-block min/max f32.
__global__ __launch_bounds__(256) void k_mask(const float* __restrict__ msO,
                                              const float* __restrict__ pan,
                                              float* __restrict__ wsF,
                                              uint* __restrict__ dv16) {
    int b = blockIdx.x;
    int gid = b * 256 + threadIdx.x;
    int base = gid * 4;
    int n = base >> 20;
    int hw = base & (HWSZ - 1);
    const float* po = msO + (size_t)n * CHW + hw;
    float sx = 0.f, sy = 0.f, sz = 0.f, sw = 0.f;
#pragma unroll
    for (int c = 0; c < NCH; ++c) {
        float4 v = *(const float4*)(po + c * HWSZ);
        sx += v.x; sy += v.y; sz += v.z; sw += v.w;
    }
    float4 pv = *(const float4*)(pan + (size_t)n * HWSZ + hw);
    float4 d;
    d.x = fabsf(sx * 0.125f - pv.x);
    d.y = fabsf(sy * 0.125f - pv.y);
    d.z = fabsf(sz * 0.125f - pv.z);
    d.w = fabsf(sw * 0.125f - pv.w);
    uint2 dpk;
    dpk.x = pknorm(d.x, d.y);
    dpk.y = pknorm(d.z, d.w);
    *(uint2*)(dv16 + (base >> 1)) = dpk;

    float m = fminf(fminf(d.x, d.y), fminf(d.z, d.w));
    float M = fmaxf(fmaxf(d.x, d.y), fmaxf(d.z, d.w));
#pragma unroll
    for (int off = 32; off > 0; off >>= 1) {
        m = fminf(m, __shfl_down(m, off));
        M = fmaxf(M, __shfl_down(M, off));
    }
    __shared__ float sm[4], sM[4];
    int wid = threadIdx.x >> 6, lane = threadIdx.x & 63;
    if (lane == 0) { sm[wid] = m; sM[wid] = M; }
    __syncthreads();
    if (threadIdx.x == 0) {
        wsF[b] = fminf(fminf(sm[0], sm[1]), fminf(sm[2], sm[3]));
        wsF[2048 + b] = fmaxf(fmaxf(sM[0], sM[1]), fmaxf(sM[2], sM[3]));
        if (b == 0) {
            wsF[WS_SUM] = 0.f;
            wsF[WS_CNT] = 0.f;
            ((unsigned*)wsF)[WS_TKT] = 0u;
        }
    }
}

// Pass 2: 1-wave block = half row, 8 px/lane. Per di: 12 DMA insts copy the
// pre-baked qt record (identity copy, halos included) into a single 12.3 KB
// LDS buffer; vmcnt(0); sliding E/O sad_u16 compute. 13 blocks/CU.
__global__ __launch_bounds__(64, 4) void k_main(const float* __restrict__ ms,
                                                const uint4* __restrict__ qt4,
                                                float* __restrict__ wsF,
                                                const uint* __restrict__ dv16,
                                                float* __restrict__ out) {
    __shared__ __align__(16) uint ldsU[4 * 768]; // 4 planes x 192 uint4 = 12288 B
    const int t = threadIdx.x;        // 0..63
    const int b = blockIdx.x;
    const int xcd = b & 7;
    const int idx = b >> 3;           // 0..511
    const int hb = idx & 1;
    const int r = idx >> 1;           // 0..255
    const int n = r >> 7;
    const int h = xcd * 128 + (r & 127);
    const int w0 = hb * 512 + 8 * t;

    // ms fragment: 8 ch x 8 px -> 4 chpair planes x 8 u32
    const float* msBase = ms + (size_t)n * CHW + (size_t)h * WW + w0;
    uint msq[4][8];
#pragma unroll
    for (int cp = 0; cp < 4; ++cp) {
        float4 a0 = *(const float4*)(msBase + (2 * cp) * HWSZ);
        float4 a1 = *(const float4*)(msBase + (2 * cp) * HWSZ + 4);
        float4 b0 = *(const float4*)(msBase + (2 * cp + 1) * HWSZ);
        float4 b1 = *(const float4*)(msBase + (2 * cp + 1) * HWSZ + 4);
        msq[cp][0] = pknorm(a0.x, b0.x); msq[cp][1] = pknorm(a0.y, b0.y);
        msq[cp][2] = pknorm(a0.z, b0.z); msq[cp][3] = pknorm(a0.w, b0.w);
        msq[cp][4] = pknorm(a1.x, b1.x); msq[cp][5] = pknorm(a1.y, b1.y);
        msq[cp][6] = pknorm(a1.z, b1.z); msq[cp][7] = pknorm(a1.w, b1.w);
    }

    uint minv[8];
#pragma unroll
    for (int p = 0; p < 8; ++p) minv[p] = 0xffffffffu;

    for (int di = 0; di < 9; ++di) {
        int gr = reflect_idx(h + (di - 4) * 4);
        // stage: identity copy of 4 records (136 used uint4 each; DMA 192)
#pragma unroll
        for (int cp = 0; cp < 4; ++cp) {
            const uint* qr = (const uint*)(qt4 +
                ((((size_t)(n * 4 + cp) << 10) + gr) * 2 + hb) * 136);
            GLD16(qr + 4 * t,        &ldsU[cp * 768]);
            GLD16(qr + 1024 + 4 * t, &ldsU[cp * 768 + 256]);
            GLD16(qr + 2048 + 4 * t, &ldsU[cp * 768 + 512]);
        }
        asm volatile("s_waitcnt vmcnt(0)" ::: "memory");

        // sliding E/O windows, stride-1 slot reads (conflict-free)
        uint4 winE[4], winO[4];
#pragma unroll
        for (int cp = 0; cp < 4; ++cp) {
            winE[cp] = *(const uint4*)(ldsU + cp * 768 + 4 * t);
            winO[cp] = *(const uint4*)(ldsU + cp * 768 + 272 + 4 * t);
        }
#pragma unroll
        for (int dj = 0; dj < 9; ++dj) {
            uint acc[8] = {0, 0, 0, 0, 0, 0, 0, 0};
#pragma unroll
            for (int cp = 0; cp < 4; ++cp) {
                uint4 lo = (dj & 1) ? winO[cp] : winE[cp];
                uint4 hi = (dj & 1) ? winE[cp] : winO[cp];
                acc[0] = sadu16(msq[cp][0], lo.x, acc[0]);
                acc[1] = sadu16(msq[cp][1], lo.y, acc[1]);
                acc[2] = sadu16(msq[cp][2], lo.z, acc[2]);
                acc[3] = sadu16(msq[cp][3], lo.w, acc[3]);
                acc[4] = sadu16(msq[cp][4], hi.x, acc[4]);
                acc[5] = sadu16(msq[cp][5], hi.y, acc[5]);
                acc[6] = sadu16(msq[cp][6], hi.z, acc[6]);
                acc[7] = sadu16(msq[cp][7], hi.w, acc[7]);
            }
#pragma unroll
            for (int p = 0; p < 8; ++p) minv[p] = min(minv[p], acc[p]);
            if (dj < 8) {
                int m = dj >> 1;
                if ((dj & 1) == 0) {
#pragma unroll
                    for (int cp = 0; cp < 4; ++cp)
                        winE[cp] = *(const uint4*)(ldsU + cp * 768 + 4 * (t + m + 1));
                } else {
#pragma unroll
                    for (int cp = 0; cp < 4; ++cp)
                        winO[cp] = *(const uint4*)(ldsU + cp * 768 + 272 + 4 * (t + m + 1));
                }
            }
        }
    }

    // ---- epilogue (single wave) ----
    float lmin = 1.0e38f, lmax = -1.0e38f;
#pragma unroll
    for (int k = 0; k < 8; ++k) {
        float4 v = ((const float4*)wsF)[k * 64 + t];
        float4 w = ((const float4*)(wsF + 2048))[k * 64 + t];
        lmin = fminf(lmin, fminf(fminf(v.x, v.y), fminf(v.z, v.w)));
        lmax = fmaxf(lmax, fmaxf(fmaxf(w.x, w.y), fmaxf(w.z, w.w)));
    }
#pragma unroll
    for (int off = 32; off > 0; off >>= 1) {
        lmin = fminf(lmin, __shfl_xor(lmin, off));
        lmax = fmaxf(lmax, __shfl_xor(lmax, off));
    }
    float thresh = lmin + (lmax - lmin) * (10.0f / 255.0f);

    uint4 dq = *(const uint4*)(dv16 + (((size_t)n * HWSZ + (size_t)h * WW + w0) >> 1));
    const float inv = 1.0f / 65535.0f;
    float lsum = 0.f, lcnt = 0.f;
    uint dw[4] = {dq.x, dq.y, dq.z, dq.w};
#pragma unroll
    for (int p = 0; p < 4; ++p) {
        float d0 = (float)(dw[p] & 0xffffu) * inv;
        float d1 = (float)(dw[p] >> 16) * inv;
        if (d0 > thresh) { lsum += (float)minv[2 * p] * inv; lcnt += 1.f; }
        if (d1 > thresh) { lsum += (float)minv[2 * p + 1] * inv; lcnt += 1.f; }
    }
#pragma unroll
    for (int off = 32; off > 0; off >>= 1) {
        lsum += __shfl_down(lsum, off);
        lcnt += __shfl_down(lcnt, off);
    }
    if (t == 0) {
        atomicAdd(&wsF[WS_SUM], lsum);
        atomicAdd(&wsF[WS_CNT], lcnt);
        __threadfence();
        unsigned tk = atomicAdd((unsigned*)&wsF[WS_TKT], 1u);
        if (tk == NBLK_MAIN - 1) {
            float s = atomicAdd(&wsF[WS_SUM], 0.f);
            float c = atomicAdd(&wsF[WS_CNT], 0.f);
            out[0] = (c > 0.f) ? (s / fmaxf(c, 1.f)) : 0.f;
        }
    }
}

extern "C" void kernel_launch(void* const* d_in, const int* in_sizes, int n_in,
                              void* d_out, int out_size, void* d_ws, size_t ws_size,
                              hipStream_t stream) {
    const float* ms  = (const float*)d_in[0];
    const float* tgt = (const float*)d_in[1];
    const float* msO = (const float*)d_in[2];
    const float* pan = (const float*)d_in[3];
    float* out = (float*)d_out;
    float* wsF = (float*)d_ws;
    uint* dv16 = (uint*)d_ws + WS_DV16;
    uint4* qt4 = (uint4*)((uint*)d_ws + WS_QT16);

    k_quant<<<NIMG * 4 * 1024, 256, 0, stream>>>(tgt, qt4);
    k_mask<<<NBLK_MASK, 256, 0, stream>>>(msO, pan, wsF, dv16);
    k_main<<<NBLK_MAIN, 64, 0, stream>>>(ms, qt4, wsF, dv16, out);
}

// Round 7
// 307.798 us; speedup vs baseline: 1.2296x; 1.2296x over previous
//
#include <hip/hip_runtime.h>

#define WW 1024
#define HH 1024
#define NIMG 2
#define NCH 8
#define HWSZ (HH * WW)
#define CHW (NCH * HWSZ)
#define NBLK_MASK 2048
#define NBLK_MAIN 1024
// ws u32 layout: [0..2047] block mins, [2048..4095] block maxs,
// [4096] sum, [4097] cnt, [4098] ticket,
// dv16 (packed unorm16 mask diff, 1M u32) at 4352, qt records at WS_QT16.
#define WS_SUM 4096
#define WS_CNT 4097
#define WS_TKT 4098
#define WS_DV16 4352
#define WS_QT16 (4352 + HWSZ)

typedef unsigned int uint;

__device__ __forceinline__ uint pknorm(float a, float b) {
    uint d;
    asm("v_cvt_pknorm_u16_f32 %0, %1, %2" : "=v"(d) : "v"(a), "v"(b));
    return d;
}
__device__ __forceinline__ uint sadu16(uint a, uint b, uint c) {
    uint d;
    asm("v_sad_u16 %0, %1, %2, %3" : "=v"(d) : "v"(a), "v"(b), "v"(c));
    return d;
}
__device__ __forceinline__ int reflect_idx(int t) {
    if (t < 0) t = -t;
    if (t > HH - 1) t = 2 * (HH - 1) - t;
    return t;
}
__device__ __forceinline__ int gp2slot(int gp) {
    return (gp & 1) ? (68 + (gp >> 1)) : (gp >> 1);
}

#define GLD16(g, l)                                                         \
    __builtin_amdgcn_global_load_lds(                                       \
        (const __attribute__((address_space(1))) uint*)(g),                 \
        (__attribute__((address_space(3))) uint*)(l), 16, 0, 0)

// Pass 0: quantize tgt to unorm16 chpairs; per (n,cp,row,half) a 136-uint4 record,
// E/O-slot-indexed with reflected col-halos baked in. (unchanged from R6 - verified)
__global__ __launch_bounds__(256) void k_quant(const float* __restrict__ tgt,
                                               uint4* __restrict__ qt4) {
    int b = blockIdx.x;            // (n*4+cp)*1024 + row
    int t = threadIdx.x;           // image granule 0..255
    int row = b & 1023;
    int pcp = b >> 10;
    int n = pcp >> 2, cp = pcp & 3;
    const float* c0 = tgt + (size_t)(n * NCH + 2 * cp) * HWSZ + (size_t)row * WW;

    float4 a = *(const float4*)(c0 + 4 * t);
    float4 c = *(const float4*)(c0 + 4 * t + HWSZ);
    uint4 u;
    u.x = pknorm(a.x, c.x); u.y = pknorm(a.y, c.y);
    u.z = pknorm(a.z, c.z); u.w = pknorm(a.w, c.w);

    uint4* rbase = qt4 + (((size_t)b) * 2) * 136;
    int g = t;
    if (g <= 131) rbase[gp2slot(g + 4)] = u;
    if (g >= 124) rbase[136 + gp2slot(g - 124)] = u;

    if (t < 8) {
        int which = t >> 2;
        int gp = (t & 3) + (which ? 132 : 0);
        uint4 hv;
        uint* hw = (uint*)&hv;
#pragma unroll
        for (int k = 0; k < 4; ++k) {
            int pc = 4 * gp + k;
            int j = which ? (1550 - pc) : (16 - pc);
            hw[k] = pknorm(c0[j], c0[j + HWSZ]);
        }
        rbase[which * 136 + gp2slot(gp)] = hv;
    }
}

// Pass 1: mask diff -> packed unorm16; per-block min/max. (unchanged from R6)
__global__ __launch_bounds__(256) void k_mask(const float* __restrict__ msO,
                                              const float* __restrict__ pan,
                                              float* __restrict__ wsF,
                                              uint* __restrict__ dv16) {
    int b = blockIdx.x;
    int gid = b * 256 + threadIdx.x;
    int base = gid * 4;
    int n = base >> 20;
    int hw = base & (HWSZ - 1);
    const float* po = msO + (size_t)n * CHW + hw;
    float sx = 0.f, sy = 0.f, sz = 0.f, sw = 0.f;
#pragma unroll
    for (int c = 0; c < NCH; ++c) {
        float4 v = *(const float4*)(po + c * HWSZ);
        sx += v.x; sy += v.y; sz += v.z; sw += v.w;
    }
    float4 pv = *(const float4*)(pan + (size_t)n * HWSZ + hw);
    float4 d;
    d.x = fabsf(sx * 0.125f - pv.x);
    d.y = fabsf(sy * 0.125f - pv.y);
    d.z = fabsf(sz * 0.125f - pv.z);
    d.w = fabsf(sw * 0.125f - pv.w);
    uint2 dpk;
    dpk.x = pknorm(d.x, d.y);
    dpk.y = pknorm(d.z, d.w);
    *(uint2*)(dv16 + (base >> 1)) = dpk;

    float m = fminf(fminf(d.x, d.y), fminf(d.z, d.w));
    float M = fmaxf(fmaxf(d.x, d.y), fmaxf(d.z, d.w));
#pragma unroll
    for (int off = 32; off > 0; off >>= 1) {
        m = fminf(m, __shfl_down(m, off));
        M = fmaxf(M, __shfl_down(M, off));
    }
    __shared__ float sm[4], sM[4];
    int wid = threadIdx.x >> 6, lane = threadIdx.x & 63;
    if (lane == 0) { sm[wid] = m; sM[wid] = M; }
    __syncthreads();
    if (threadIdx.x == 0) {
        wsF[b] = fminf(fminf(sm[0], sm[1]), fminf(sm[2], sm[3]));
        wsF[2048 + b] = fmaxf(fmaxf(sM[0], sM[1]), fmaxf(sM[2], sM[3]));
        if (b == 0) {
            wsF[WS_SUM] = 0.f;
            wsF[WS_CNT] = 0.f;
            ((unsigned*)wsF)[WS_TKT] = 0u;
        }
    }
}

// Pass 2: 1-wave block = half-row lattice cell; processes 4 output rows (stride 4)
// over a 9-slot LDS ring of staged target rows. 12 stages per block (vs 36 in R6).
// Steady-state staging = global->VGPR prefetch during compute + ds_write after.
__global__ __launch_bounds__(64, 2) void k_main(const float* __restrict__ ms,
                                                const uint4* __restrict__ qt4,
                                                float* __restrict__ wsF,
                                                const uint* __restrict__ dv16,
                                                float* __restrict__ out) {
    __shared__ __align__(16) uint4 lds4[9 * 4 * 136]; // 76.5 KB ring
    const int t = threadIdx.x;        // 0..63
    const int b = blockIdx.x;         // 0..1023
    const int xcd = b & 7;
    const int q = b >> 3;             // 0..127
    const int n = q >> 6;
    const int r = q & 63;
    const int hb = r >> 5;
    const int w = r & 31;
    const int h0 = xcd * 128 + 16 * (w >> 2) + (w & 3);
    const int w0 = hb * 512 + 8 * t;

    // ---- prologue: stage s=0..8 into ring slots 0..8 ----
    // full 2x64-uint4 chunks via GLD16 (sources at u32 +0 / +256 — R6 bug fixed)
#pragma unroll
    for (int s = 0; s < 9; ++s) {
        int row = reflect_idx(h0 + 4 * (s - 4));
#pragma unroll
        for (int cp = 0; cp < 4; ++cp) {
            const uint* rec = (const uint*)(qt4 +
                ((((size_t)(n * 4 + cp) << 10) + row) * 2 + hb) * 136);
            uint* dst = (uint*)&lds4[(s * 4 + cp) * 136];
            GLD16(rec + 4 * t, dst);
            GLD16(rec + 256 + 4 * t, dst + 256);
        }
    }
    // tails (8 uint4 per record): 288 items over 64 lanes x 5 iters, via registers
#pragma unroll
    for (int j = 0; j < 5; ++j) {
        int id = t + 64 * j;
        if (id < 288) {
            int s = id >> 5, rem = id & 31, cp = rem >> 3, e = rem & 7;
            int row = reflect_idx(h0 + 4 * (s - 4));
            const uint4* rec = qt4 +
                ((((size_t)(n * 4 + cp) << 10) + row) * 2 + hb) * 136;
            lds4[(s * 4 + cp) * 136 + 128 + e] = rec[128 + e];
        }
    }
    asm volatile("s_waitcnt vmcnt(0)" ::: "memory"); // GLD16 completion = vmcnt

    // ---- global mask min/max (k_mask finished before this kernel) ----
    float lmin = 1.0e38f, lmax = -1.0e38f;
#pragma unroll
    for (int k = 0; k < 8; ++k) {
        float4 v = ((const float4*)wsF)[k * 64 + t];
        float4 x = ((const float4*)(wsF + 2048))[k * 64 + t];
        lmin = fminf(lmin, fminf(fminf(v.x, v.y), fminf(v.z, v.w)));
        lmax = fmaxf(lmax, fmaxf(fmaxf(x.x, x.y), fmaxf(x.z, x.w)));
    }
#pragma unroll
    for (int off = 32; off > 0; off >>= 1) {
        lmin = fminf(lmin, __shfl_xor(lmin, off));
        lmax = fmaxf(lmax, __shfl_xor(lmax, off));
    }
    const float thresh = lmin + (lmax - lmin) * (10.0f / 255.0f);
    const float inv = 1.0f / 65535.0f;

    float lsum = 0.f, lcnt = 0.f;

    for (int k = 0; k < 4; ++k) {
        const int oh = h0 + 4 * k;

        // ms fragment for this output row
        const float* msBase = ms + (size_t)n * CHW + (size_t)oh * WW + w0;
        uint msq[4][8];
#pragma unroll
        for (int cp = 0; cp < 4; ++cp) {
            float4 a0 = *(const float4*)(msBase + (2 * cp) * HWSZ);
            float4 a1 = *(const float4*)(msBase + (2 * cp) * HWSZ + 4);
            float4 b0 = *(const float4*)(msBase + (2 * cp + 1) * HWSZ);
            float4 b1 = *(const float4*)(msBase + (2 * cp + 1) * HWSZ + 4);
            msq[cp][0] = pknorm(a0.x, b0.x); msq[cp][1] = pknorm(a0.y, b0.y);
            msq[cp][2] = pknorm(a0.z, b0.z); msq[cp][3] = pknorm(a0.w, b0.w);
            msq[cp][4] = pknorm(a1.x, b1.x); msq[cp][5] = pknorm(a1.y, b1.y);
            msq[cp][6] = pknorm(a1.z, b1.z); msq[cp][7] = pknorm(a1.w, b1.w);
        }

        // prefetch stage k+9 into registers (latency hidden by the di loop below)
        uint4 pf[4][2], pft;
        const bool havePf = (k < 3);
        if (havePf) {
            int prow = reflect_idx(h0 + 4 * (k + 5));
#pragma unroll
            for (int cp = 0; cp < 4; ++cp) {
                const uint4* rec = qt4 +
                    ((((size_t)(n * 4 + cp) << 10) + prow) * 2 + hb) * 136;
                pf[cp][0] = rec[t];
                pf[cp][1] = rec[64 + t];
            }
            if (t < 32) {
                const uint4* rec = qt4 +
                    ((((size_t)(n * 4 + (t >> 3)) << 10) + prow) * 2 + hb) * 136;
                pft = rec[128 + (t & 7)];
            }
        }

        uint minv[8];
#pragma unroll
        for (int p = 0; p < 8; ++p) minv[p] = 0xffffffffu;

        for (int di = 0; di < 9; ++di) {
            int slot = k + di; if (slot >= 9) slot -= 9;
            const uint4* sl = &lds4[(slot * 4) * 136];
            uint4 winE[4], winO[4];
#pragma unroll
            for (int cp = 0; cp < 4; ++cp) {
                winE[cp] = sl[cp * 136 + t];
                winO[cp] = sl[cp * 136 + 68 + t];
            }
#pragma unroll
            for (int dj = 0; dj < 9; ++dj) {
                uint acc[8] = {0, 0, 0, 0, 0, 0, 0, 0};
#pragma unroll
                for (int cp = 0; cp < 4; ++cp) {
                    uint4 lo = (dj & 1) ? winO[cp] : winE[cp];
                    uint4 hi = (dj & 1) ? winE[cp] : winO[cp];
                    acc[0] = sadu16(msq[cp][0], lo.x, acc[0]);
                    acc[1] = sadu16(msq[cp][1], lo.y, acc[1]);
                    acc[2] = sadu16(msq[cp][2], lo.z, acc[2]);
                    acc[3] = sadu16(msq[cp][3], lo.w, acc[3]);
                    acc[4] = sadu16(msq[cp][4], hi.x, acc[4]);
                    acc[5] = sadu16(msq[cp][5], hi.y, acc[5]);
                    acc[6] = sadu16(msq[cp][6], hi.z, acc[6]);
                    acc[7] = sadu16(msq[cp][7], hi.w, acc[7]);
                }
#pragma unroll
                for (int p = 0; p < 8; ++p) minv[p] = min(minv[p], acc[p]);
                if (dj < 8) {
                    int m = dj >> 1;
                    if ((dj & 1) == 0) {
#pragma unroll
                        for (int cp = 0; cp < 4; ++cp)
                            winE[cp] = sl[cp * 136 + (t + m + 1)];
                    } else {
#pragma unroll
                        for (int cp = 0; cp < 4; ++cp)
                            winO[cp] = sl[cp * 136 + 68 + (t + m + 1)];
                    }
                }
            }
        }

        // retire ring slot k%9 with the prefetched stage k+9
        if (havePf) {
            uint4* dst = &lds4[((k % 9) * 4) * 136];
#pragma unroll
            for (int cp = 0; cp < 4; ++cp) {
                dst[cp * 136 + t] = pf[cp][0];
                dst[cp * 136 + 64 + t] = pf[cp][1];
            }
            if (t < 32) dst[(t >> 3) * 136 + 128 + (t & 7)] = pft;
        }

        // masked accumulate for this output row
        uint4 dq = *(const uint4*)(dv16 + (((size_t)n * HWSZ + (size_t)oh * WW + w0) >> 1));
        uint dw[4] = {dq.x, dq.y, dq.z, dq.w};
#pragma unroll
        for (int p = 0; p < 4; ++p) {
            float d0 = (float)(dw[p] & 0xffffu) * inv;
            float d1 = (float)(dw[p] >> 16) * inv;
            if (d0 > thresh) { lsum += (float)minv[2 * p] * inv; lcnt += 1.f; }
            if (d1 > thresh) { lsum += (float)minv[2 * p + 1] * inv; lcnt += 1.f; }
        }
    }

#pragma unroll
    for (int off = 32; off > 0; off >>= 1) {
        lsum += __shfl_down(lsum, off);
        lcnt += __shfl_down(lcnt, off);
    }
    if (t == 0) {
        atomicAdd(&wsF[WS_SUM], lsum);
        atomicAdd(&wsF[WS_CNT], lcnt);
        __threadfence();
        unsigned tk = atomicAdd((unsigned*)&wsF[WS_TKT], 1u);
        if (tk == NBLK_MAIN - 1) {
            float s = atomicAdd(&wsF[WS_SUM], 0.f);
            float c = atomicAdd(&wsF[WS_CNT], 0.f);
            out[0] = (c > 0.f) ? (s / fmaxf(c, 1.f)) : 0.f;
        }
    }
}

extern "C" void kernel_launch(void* const* d_in, const int* in_sizes, int n_in,
                              void* d_out, int out_size, void* d_ws, size_t ws_size,
                              hipStream_t stream) {
    const float* ms  = (const float*)d_in[0];
    const float* tgt = (const float*)d_in[1];
    const float* msO = (const float*)d_in[2];
    const float* pan = (const float*)d_in[3];
    float* out = (float*)d_out;
    float* wsF = (float*)d_ws;
    uint* dv16 = (uint*)d_ws + WS_DV16;
    uint4* qt4 = (uint4*)((uint*)d_ws + WS_QT16);

    k_quant<<<NIMG * 4 * 1024, 256, 0, stream>>>(tgt, qt4);
    k_mask<<<NBLK_MASK, 256, 0, stream>>>(msO, pan, wsF, dv16);
    k_main<<<NBLK_MAIN, 64, 0, stream>>>(ms, qt4, wsF, dv16, out);
}

// Round 8
// 273.467 us; speedup vs baseline: 1.3840x; 1.1255x over previous
//
#include <hip/hip_runtime.h>

#define WW 1024
#define HH 1024
#define NIMG 2
#define NCH 8
#define HWSZ (HH * WW)
#define CHW (NCH * HWSZ)
#define NBLK_MASK 2048
#define NBLK_MAIN 1024
// ws u32 layout: [0..2047] block mins, [2048..4095] block maxs,
// [4096] sum, [4097] cnt, [4098] ticket,
// dv16 (packed unorm16 mask diff) at 4352, u8 qt records at WS_QT.
#define WS_SUM 4096
#define WS_CNT 4097
#define WS_TKT 4098
#define WS_DV16 4352
#define WS_QT (4352 + HWSZ)
#define RECU4 320   // uint4 per (n,row,half) record: [p0 136][p1 136][pad 48]
#define SLOTU 1280  // u32 per LDS ring slot (= record size)

typedef unsigned int uint;

__device__ __forceinline__ uint pknorm(float a, float b) {
    uint d;
    asm("v_cvt_pknorm_u16_f32 %0, %1, %2" : "=v"(d) : "v"(a), "v"(b));
    return d;
}
__device__ __forceinline__ uint sadu8(uint a, uint b, uint c) {
    uint d;
    asm("v_sad_u8 %0, %1, %2, %3" : "=v"(d) : "v"(a), "v"(b), "v"(c));
    return d;
}
__device__ __forceinline__ uint q8(float x) {
    return (uint)__float2int_rn(x * 255.f);
}
__device__ __forceinline__ int reflect_idx(int t) {
    if (t < 0) t = -t;
    if (t > HH - 1) t = 2 * (HH - 1) - t;
    return t;
}
// padded granule (0..135) -> E/O slot (E first, then O)
__device__ __forceinline__ int gp2slot(int gp) {
    return (gp & 1) ? (68 + (gp >> 1)) : (gp >> 1);
}

#define GLD16(g, l)                                                         \
    __builtin_amdgcn_global_load_lds(                                       \
        (const __attribute__((address_space(1))) uint*)(g),                 \
        (__attribute__((address_space(3))) uint*)(l), 16, 0, 0)

// Pass 0: quantize tgt to u8 (4 ch per u32); per (n,row,half) a 320-uint4 record
// [p0: E68|O68][p1: E68|O68][pad], reflected col-halos baked in.
__global__ __launch_bounds__(256) void k_quant(const float* __restrict__ tgt,
                                               uint4* __restrict__ qt4) {
    int b = blockIdx.x;            // (n*2+p)*1024 + row
    int t = threadIdx.x;           // image granule (4 px)
    int row = b & 1023;
    int np = b >> 10;
    int n = np >> 1, p = np & 1;
    const float* c0 = tgt + (size_t)(n * NCH + 4 * p) * HWSZ + (size_t)row * WW;

    float4 v0 = *(const float4*)(c0 + 4 * t);
    float4 v1 = *(const float4*)(c0 + HWSZ + 4 * t);
    float4 v2 = *(const float4*)(c0 + 2 * HWSZ + 4 * t);
    float4 v3 = *(const float4*)(c0 + 3 * HWSZ + 4 * t);
    uint4 u;
    u.x = q8(v0.x) | (q8(v1.x) << 8) | (q8(v2.x) << 16) | (q8(v3.x) << 24);
    u.y = q8(v0.y) | (q8(v1.y) << 8) | (q8(v2.y) << 16) | (q8(v3.y) << 24);
    u.z = q8(v0.z) | (q8(v1.z) << 8) | (q8(v2.z) << 16) | (q8(v3.z) << 24);
    u.w = q8(v0.w) | (q8(v1.w) << 8) | (q8(v2.w) << 16) | (q8(v3.w) << 24);

    size_t rb = ((size_t)((n << 10) + row)) * 2;
    int h1 = t >> 7;
    int gp = (t & 127) + 4;        // 4..131 within own half
    qt4[(rb + h1) * RECU4 + p * 136 + gp2slot(gp)] = u;
    // interior overlap granules (appear in the other half's halo region)
    if (t >= 124 && t < 128)
        qt4[(rb + 1) * RECU4 + p * 136 + gp2slot(t - 124)] = u;
    if (t >= 128 && t < 132)
        qt4[(rb + 0) * RECU4 + p * 136 + gp2slot(t - 128 + 132)] = u;
    // reflected edge halos: 32 scalar u32 (one px each)
    if (t < 32) {
        int which = t >> 4, m = t & 15;
        int pc = which ? (528 + m) : m;          // padded col
        int j = which ? (1022 - m) : (16 - m);   // reflected image col
        uint val = q8(c0[j]) | (q8(c0[j + HWSZ]) << 8) |
                   (q8(c0[j + 2 * HWSZ]) << 16) | (q8(c0[j + 3 * HWSZ]) << 24);
        uint* recU = (uint*)(qt4 + (rb + which) * RECU4);
        recU[p * 544 + gp2slot(pc >> 2) * 4 + (pc & 3)] = val;
    }
}

// Pass 1: mask diff -> packed unorm16; per-block min/max. (verified, unchanged)
__global__ __launch_bounds__(256) void k_mask(const float* __restrict__ msO,
                                              const float* __restrict__ pan,
                                              float* __restrict__ wsF,
                                              uint* __restrict__ dv16) {
    int b = blockIdx.x;
    int gid = b * 256 + threadIdx.x;
    int base = gid * 4;
    int n = base >> 20;
    int hw = base & (HWSZ - 1);
    const float* po = msO + (size_t)n * CHW + hw;
    float sx = 0.f, sy = 0.f, sz = 0.f, sw = 0.f;
#pragma unroll
    for (int c = 0; c < NCH; ++c) {
        float4 v = *(const float4*)(po + c * HWSZ);
        sx += v.x; sy += v.y; sz += v.z; sw += v.w;
    }
    float4 pv = *(const float4*)(pan + (size_t)n * HWSZ + hw);
    float4 d;
    d.x = fabsf(sx * 0.125f - pv.x);
    d.y = fabsf(sy * 0.125f - pv.y);
    d.z = fabsf(sz * 0.125f - pv.z);
    d.w = fabsf(sw * 0.125f - pv.w);
    uint2 dpk;
    dpk.x = pknorm(d.x, d.y);
    dpk.y = pknorm(d.z, d.w);
    *(uint2*)(dv16 + (base >> 1)) = dpk;

    float m = fminf(fminf(d.x, d.y), fminf(d.z, d.w));
    float M = fmaxf(fmaxf(d.x, d.y), fmaxf(d.z, d.w));
#pragma unroll
    for (int off = 32; off > 0; off >>= 1) {
        m = fminf(m, __shfl_down(m, off));
        M = fmaxf(M, __shfl_down(M, off));
    }
    __shared__ float sm[4], sM[4];
    int wid = threadIdx.x >> 6, lane = threadIdx.x & 63;
    if (lane == 0) { sm[wid] = m; sM[wid] = M; }
    __syncthreads();
    if (threadIdx.x == 0) {
        wsF[b] = fminf(fminf(sm[0], sm[1]), fminf(sm[2], sm[3]));
        wsF[2048 + b] = fmaxf(fmaxf(sM[0], sM[1]), fmaxf(sM[2], sM[3]));
        if (b == 0) {
            wsF[WS_SUM] = 0.f;
            wsF[WS_CNT] = 0.f;
            ((unsigned*)wsF)[WS_TKT] = 0u;
        }
    }
}

// Pass 2: 1-wave block = half-row band (4 output rows, stride 4) over a 10-slot
// u8 DMA ring. Per di: 20-b128 burst into register windows; v_sad_u8 inner loop.
__global__ __launch_bounds__(64) void k_main(const float* __restrict__ ms,
                                             const uint4* __restrict__ qt4,
                                             float* __restrict__ wsF,
                                             const uint* __restrict__ dv16,
                                             float* __restrict__ out) {
    __shared__ __align__(16) uint ldsU[10 * SLOTU]; // 51.2 KB -> 3 blocks/CU
    const int t = threadIdx.x;        // 0..63
    const int b = blockIdx.x;         // 0..1023
    const int xcd = b & 7;
    const int q = b >> 3;             // 0..127
    const int n = q >> 6;
    const int r = q & 63;
    const int hb = r >> 5;
    const int w = r & 31;
    const int h0 = xcd * 128 + 16 * (w >> 2) + (w & 3);
    const int w0 = hb * 512 + 8 * t;

    // ---- mask min/max loads first (so their waitcnt doesn't drain stage DMA) ----
    float lmin = 1.0e38f, lmax = -1.0e38f;
#pragma unroll
    for (int k = 0; k < 8; ++k) {
        float4 v = ((const float4*)wsF)[k * 64 + t];
        float4 x = ((const float4*)(wsF + 2048))[k * 64 + t];
        lmin = fminf(lmin, fminf(fminf(v.x, v.y), fminf(v.z, v.w)));
        lmax = fmaxf(lmax, fmaxf(fmaxf(x.x, x.y), fmaxf(x.z, x.w)));
    }

    // ---- prologue: stage s=0..9 into ring slots 0..9 (5 GLD16 each) ----
    const size_t recStride2 = 2;      // records per row (halves)
    const size_t nBase = ((size_t)n << 10);
#pragma unroll 1
    for (int s = 0; s < 10; ++s) {
        int row = reflect_idx(h0 + 4 * (s - 4));
        const uint* rec = (const uint*)(qt4 + ((nBase + row) * recStride2 + hb) * RECU4);
#pragma unroll
        for (int c = 0; c < 5; ++c)
            GLD16(rec + c * 256 + 4 * t, &ldsU[s * SLOTU + c * 256]);
    }

#pragma unroll
    for (int off = 32; off > 0; off >>= 1) {
        lmin = fminf(lmin, __shfl_xor(lmin, off));
        lmax = fmaxf(lmax, __shfl_xor(lmax, off));
    }
    const float thresh = lmin + (lmax - lmin) * (10.0f / 255.0f);
    const float inv16 = 1.0f / 65535.0f;
    const float inv8 = 1.0f / 255.0f;

    asm volatile("s_waitcnt vmcnt(0)" ::: "memory");

    float lsum = 0.f, lcnt = 0.f;

#pragma unroll 1
    for (int k = 0; k < 4; ++k) {
        const int oh = h0 + 4 * k;

        // ms fragment: 8 px x 8 ch -> msq[2][8] (u8-packed), loads issued first
        const float* msBase = ms + (size_t)n * CHW + (size_t)oh * WW + w0;
        float4 A[2][4][2];
#pragma unroll
        for (int p = 0; p < 2; ++p)
#pragma unroll
            for (int cc = 0; cc < 4; ++cc) {
                A[p][cc][0] = *(const float4*)(msBase + (size_t)(4 * p + cc) * HWSZ);
                A[p][cc][1] = *(const float4*)(msBase + (size_t)(4 * p + cc) * HWSZ + 4);
            }
        uint4 dq = *(const uint4*)(dv16 + (((size_t)n * HWSZ + (size_t)oh * WW + w0) >> 1));

        // steady-state stage: row s=k+9 into dead slot k-1 (k=1,2)
        if (k == 1 || k == 2) {
            int prow = reflect_idx(h0 + 4 * (k + 5));
            const uint* rec = (const uint*)(qt4 + ((nBase + prow) * recStride2 + hb) * RECU4);
#pragma unroll
            for (int c = 0; c < 5; ++c)
                GLD16(rec + c * 256 + 4 * t, &ldsU[(k - 1) * SLOTU + c * 256]);
        }

        uint msq[2][8];
#pragma unroll
        for (int p = 0; p < 2; ++p) {
#pragma unroll
            for (int half = 0; half < 2; ++half) {
                float4 c0 = A[p][0][half], c1 = A[p][1][half],
                       c2 = A[p][2][half], c3 = A[p][3][half];
                msq[p][4 * half + 0] = q8(c0.x) | (q8(c1.x) << 8) | (q8(c2.x) << 16) | (q8(c3.x) << 24);
                msq[p][4 * half + 1] = q8(c0.y) | (q8(c1.y) << 8) | (q8(c2.y) << 16) | (q8(c3.y) << 24);
                msq[p][4 * half + 2] = q8(c0.z) | (q8(c1.z) << 8) | (q8(c2.z) << 16) | (q8(c3.z) << 24);
                msq[p][4 * half + 3] = q8(c0.w) | (q8(c1.w) << 8) | (q8(c2.w) << 16) | (q8(c3.w) << 24);
            }
        }

        uint minv[8];
#pragma unroll
        for (int p = 0; p < 8; ++p) minv[p] = 0xffffffffu;

#pragma unroll 1
        for (int di = 0; di < 9; ++di) {
            int slot = k + di; if (slot >= 10) slot -= 10;
            const uint* sb = &ldsU[slot * SLOTU];
            // 40-px windows, all reads independent (burst): E slots t..t+4, O likewise
            uint4 winE[2][5], winO[2][5];
#pragma unroll
            for (int p = 0; p < 2; ++p)
#pragma unroll
                for (int qq = 0; qq < 5; ++qq) {
                    winE[p][qq] = *(const uint4*)(sb + p * 544 + 4 * (t + qq));
                    winO[p][qq] = *(const uint4*)(sb + p * 544 + 272 + 4 * (t + qq));
                }
            uint acc[8];
#pragma unroll
            for (int dj = 0; dj < 9; ++dj) {
#pragma unroll
                for (int p = 0; p < 8; ++p) acc[p] = 0;
#pragma unroll
                for (int p = 0; p < 2; ++p) {
                    uint4 lo = (dj & 1) ? winO[p][(dj - 1) >> 1] : winE[p][dj >> 1];
                    uint4 hi = (dj & 1) ? winE[p][(dj + 1) >> 1] : winO[p][dj >> 1];
                    acc[0] = sadu8(msq[p][0], lo.x, acc[0]);
                    acc[1] = sadu8(msq[p][1], lo.y, acc[1]);
                    acc[2] = sadu8(msq[p][2], lo.z, acc[2]);
                    acc[3] = sadu8(msq[p][3], lo.w, acc[3]);
                    acc[4] = sadu8(msq[p][4], hi.x, acc[4]);
                    acc[5] = sadu8(msq[p][5], hi.y, acc[5]);
                    acc[6] = sadu8(msq[p][6], hi.z, acc[6]);
                    acc[7] = sadu8(msq[p][7], hi.w, acc[7]);
                }
#pragma unroll
                for (int p = 0; p < 8; ++p) minv[p] = min(minv[p], acc[p]);
            }
        }
        // drain the steady-state stage before next row reads its slot
        asm volatile("s_waitcnt vmcnt(0)" ::: "memory");

        // masked accumulate for this output row
        uint dw[4] = {dq.x, dq.y, dq.z, dq.w};
#pragma unroll
        for (int p = 0; p < 4; ++p) {
            float d0 = (float)(dw[p] & 0xffffu) * inv16;
            float d1 = (float)(dw[p] >> 16) * inv16;
            if (d0 > thresh) { lsum += (float)minv[2 * p] * inv8; lcnt += 1.f; }
            if (d1 > thresh) { lsum += (float)minv[2 * p + 1] * inv8; lcnt += 1.f; }
        }
    }

#pragma unroll
    for (int off = 32; off > 0; off >>= 1) {
        lsum += __shfl_down(lsum, off);
        lcnt += __shfl_down(lcnt, off);
    }
    if (t == 0) {
        atomicAdd(&wsF[WS_SUM], lsum);
        atomicAdd(&wsF[WS_CNT], lcnt);
        __threadfence();
        unsigned tk = atomicAdd((unsigned*)&wsF[WS_TKT], 1u);
        if (tk == NBLK_MAIN - 1) {
            float s = atomicAdd(&wsF[WS_SUM], 0.f);
            float c = atomicAdd(&wsF[WS_CNT], 0.f);
            out[0] = (c > 0.f) ? (s / fmaxf(c, 1.f)) : 0.f;
        }
    }
}

extern "C" void kernel_launch(void* const* d_in, const int* in_sizes, int n_in,
                              void* d_out, int out_size, void* d_ws, size_t ws_size,
                              hipStream_t stream) {
    const float* ms  = (const float*)d_in[0];
    const float* tgt = (const float*)d_in[1];
    const float* msO = (const float*)d_in[2];
    const float* pan = (const float*)d_in[3];
    float* out = (float*)d_out;
    float* wsF = (float*)d_ws;
    uint* dv16 = (uint*)d_ws + WS_DV16;
    uint4* qt4 = (uint4*)((uint*)d_ws + WS_QT);

    k_quant<<<NIMG * 2 * 1024, 256, 0, stream>>>(tgt, qt4);
    k_mask<<<NBLK_MASK, 256, 0, stream>>>(msO, pan, wsF, dv16);
    k_main<<<NBLK_MAIN, 64, 0, stream>>>(ms, qt4, wsF, dv16, out);
}